// Round 1
// baseline (713.044 us; speedup 1.0000x reference)
//
#include <hip/hip_runtime.h>
#include <hip/hip_bf16.h>

#define D_FEAT 256

// ---------------------------------------------------------------------------
// Kernel 1: support = X @ W   (fp32, tiled 64x64x16, 256 threads, 4x4/thread)
// ---------------------------------------------------------------------------
__global__ __launch_bounds__(256) void gemm_xw(
    const float* __restrict__ X, const float* __restrict__ W,
    float* __restrict__ S, int M) {
  __shared__ float As[16][64 + 1];
  __shared__ float Bs[16][64 + 1];
  const int tid = threadIdx.x;
  const int tx = tid & 15;        // 0..15 -> output col group
  const int ty = tid >> 4;        // 0..15 -> output row group
  const int m0 = blockIdx.x * 64;
  const int n0 = blockIdx.y * 64;

  float acc[4][4] = {};

  for (int k0 = 0; k0 < D_FEAT; k0 += 16) {
    // Load A tile: rows m0..m0+63, k = k0..k0+15   (thread: row tid>>2, 4 k's)
    {
      const int r = tid >> 2;
      const int kc = (tid & 3) * 4;
      const int gr = m0 + r;
      float4 a = make_float4(0.f, 0.f, 0.f, 0.f);
      if (gr < M)
        a = *reinterpret_cast<const float4*>(X + (size_t)gr * D_FEAT + k0 + kc);
      As[kc + 0][r] = a.x;
      As[kc + 1][r] = a.y;
      As[kc + 2][r] = a.z;
      As[kc + 3][r] = a.w;
    }
    // Load B tile: k rows k0..k0+15, cols n0..n0+63 (thread: k tid>>4, 4 n's)
    {
      const int kr = tid >> 4;
      const int nc = (tid & 15) * 4;
      const float4 b =
          *reinterpret_cast<const float4*>(W + (size_t)(k0 + kr) * D_FEAT + n0 + nc);
      Bs[kr][nc + 0] = b.x;
      Bs[kr][nc + 1] = b.y;
      Bs[kr][nc + 2] = b.z;
      Bs[kr][nc + 3] = b.w;
    }
    __syncthreads();

#pragma unroll
    for (int k = 0; k < 16; ++k) {
      float a[4], b[4];
#pragma unroll
      for (int i = 0; i < 4; ++i) a[i] = As[k][ty * 4 + i];
#pragma unroll
      for (int j = 0; j < 4; ++j) b[j] = Bs[k][tx * 4 + j];
#pragma unroll
      for (int i = 0; i < 4; ++i)
#pragma unroll
        for (int j = 0; j < 4; ++j) acc[i][j] += a[i] * b[j];
    }
    __syncthreads();
  }

#pragma unroll
  for (int i = 0; i < 4; ++i) {
    const int gr = m0 + ty * 4 + i;
    if (gr < M) {
      float4 o = make_float4(acc[i][0], acc[i][1], acc[i][2], acc[i][3]);
      *reinterpret_cast<float4*>(S + (size_t)gr * D_FEAT + n0 + tx * 4) = o;
    }
  }
}

// ---------------------------------------------------------------------------
// Kernel 2: rowptr[n] = lower_bound(adj_row, n), n in [0, N]  (adj_row sorted)
// ---------------------------------------------------------------------------
__global__ __launch_bounds__(256) void build_rowptr(
    const int* __restrict__ rows, int E, int* __restrict__ ptr, int N) {
  const int n = blockIdx.x * blockDim.x + threadIdx.x;
  if (n > N) return;
  int lo = 0, hi = E;
  while (lo < hi) {
    const int mid = (lo + hi) >> 1;
    if (rows[mid] < n) lo = mid + 1; else hi = mid;
  }
  ptr[n] = lo;
}

// ---------------------------------------------------------------------------
// Kernel 3: out[n] = bias + sum_{e in [ptr[n],ptr[n+1])} val[e]*S[col[e]]
// One wave per node; lane handles 4 features (float4). No atomics.
// ---------------------------------------------------------------------------
__global__ __launch_bounds__(256) void spmm_rows(
    const float* __restrict__ S, const int* __restrict__ ptr,
    const int* __restrict__ col, const float* __restrict__ val,
    const float* __restrict__ bias, float* __restrict__ out, int N) {
  const int wave = threadIdx.x >> 6;   // 0..3
  const int lane = threadIdx.x & 63;
  const int n = blockIdx.x * 4 + wave;
  if (n >= N) return;

  const int e0 = ptr[n];
  const int e1 = ptr[n + 1];

  float4 acc = make_float4(0.f, 0.f, 0.f, 0.f);
  for (int e = e0; e < e1; ++e) {
    const int c = col[e];
    const float v = val[e];
    const float4 s =
        *reinterpret_cast<const float4*>(S + (size_t)c * D_FEAT + lane * 4);
    acc.x += v * s.x;
    acc.y += v * s.y;
    acc.z += v * s.z;
    acc.w += v * s.w;
  }
  const float4 b = *reinterpret_cast<const float4*>(bias + lane * 4);
  acc.x += b.x;
  acc.y += b.y;
  acc.z += b.z;
  acc.w += b.w;
  *reinterpret_cast<float4*>(out + (size_t)n * D_FEAT + lane * 4) = acc;
}

// ---------------------------------------------------------------------------
extern "C" void kernel_launch(void* const* d_in, const int* in_sizes, int n_in,
                              void* d_out, int out_size, void* d_ws, size_t ws_size,
                              hipStream_t stream) {
  const float* x       = (const float*)d_in[0];
  const int*   adj_row = (const int*)d_in[1];
  const int*   adj_col = (const int*)d_in[2];
  const float* adj_val = (const float*)d_in[3];
  const float* weight  = (const float*)d_in[4];
  const float* bias    = (const float*)d_in[5];
  float*       out     = (float*)d_out;

  const int N = in_sizes[0] / D_FEAT;   // 100000
  const int E = in_sizes[1];            // 3200000

  // ws layout: support [N*256 f32] | rowptr [(N+1) int]
  float* support = (float*)d_ws;
  int*   rowptr  = (int*)((char*)d_ws + (size_t)N * D_FEAT * sizeof(float));

  // 1) support = X @ W
  {
    dim3 grid((N + 63) / 64, D_FEAT / 64);
    gemm_xw<<<grid, 256, 0, stream>>>(x, weight, support, N);
  }
  // 2) CSR row pointers from sorted adj_row
  {
    const int threads = 256;
    const int blocks = (N + 1 + threads - 1) / threads;
    build_rowptr<<<blocks, threads, 0, stream>>>(adj_row, E, rowptr, N);
  }
  // 3) segment-sum gather + bias
  {
    const int blocks = (N + 3) / 4;
    spmm_rows<<<blocks, 256, 0, stream>>>(support, rowptr, adj_col, adj_val,
                                          bias, out, N);
  }
}

// Round 2
// 318.460 us; speedup vs baseline: 2.2390x; 2.2390x over previous
//
#include <hip/hip_runtime.h>
#include <hip/hip_bf16.h>

#define D_FEAT 256

typedef __attribute__((ext_vector_type(8))) __bf16 bf16x8;
typedef __attribute__((ext_vector_type(4))) __bf16 bf16x4;
typedef __attribute__((ext_vector_type(4))) float f32x4;

// ---------------------------------------------------------------------------
// Kernel 0: Wt[n][k] = bf16(W[k][n])   (256x256, tiny)
// ---------------------------------------------------------------------------
__global__ __launch_bounds__(256) void cast_wt(
    const float* __restrict__ W, __bf16* __restrict__ Wt) {
  const int n = blockIdx.x;
  const int k = threadIdx.x;
  Wt[n * 256 + k] = (__bf16)W[k * 256 + n];
}

// ---------------------------------------------------------------------------
// Kernel 1: S = bf16( X @ W )  via mfma_f32_16x16x32_bf16
// Block: 256 thr (4 waves). Tile BM=128, BN=64, BK=32.
// Wave w: rows [w*32, w*32+32) x all 64 cols -> 2x4 frags.
// A-frag: lane holds A[row0+(l&15)][k0+(l>>4)*8 + j]  (8 contiguous bf16)
// B-frag: lane holds B[k0+(l>>4)*8 + j][col0+(l&15)]  = Wt[col][k] contiguous
// D:      col = l&15, row = (l>>4)*4 + reg            (m89-verified)
// ---------------------------------------------------------------------------
#define APITCH 40  // bf16 elems per row (pad 32->40 keeps b128 2-way only)

__global__ __launch_bounds__(256) void gemm_mfma(
    const float* __restrict__ X, const __bf16* __restrict__ Wt,
    __bf16* __restrict__ S, int M) {
  __shared__ __bf16 As[128 * APITCH];  // 10 KiB
  __shared__ __bf16 Bs[64 * APITCH];   // 5 KiB
  const int tid = threadIdx.x;
  const int wave = tid >> 6;
  const int lane = tid & 63;
  const int m0 = blockIdx.x * 128;
  const int n0 = blockIdx.y * 64;

  f32x4 acc[2][4] = {};

  const int l15 = lane & 15;
  const int kh8 = (lane >> 4) * 8;

  for (int k0 = 0; k0 < D_FEAT; k0 += 32) {
    // --- stage A: 128 rows x 32 k, fp32 -> bf16 ---
    {
      const int r = tid >> 1;             // 0..127
      const int kh = (tid & 1) * 16;      // 0 or 16
      const int gr = m0 + r;
      float v[16];
      if (gr < M) {
        const float* src = X + (size_t)gr * D_FEAT + k0 + kh;
#pragma unroll
        for (int q = 0; q < 4; ++q) {
          float4 f = *reinterpret_cast<const float4*>(src + q * 4);
          v[q * 4 + 0] = f.x; v[q * 4 + 1] = f.y;
          v[q * 4 + 2] = f.z; v[q * 4 + 3] = f.w;
        }
      } else {
#pragma unroll
        for (int q = 0; q < 16; ++q) v[q] = 0.f;
      }
      bf16x8 b0, b1;
#pragma unroll
      for (int q = 0; q < 8; ++q) { b0[q] = (__bf16)v[q]; b1[q] = (__bf16)v[q + 8]; }
      *reinterpret_cast<bf16x8*>(&As[r * APITCH + kh]) = b0;
      *reinterpret_cast<bf16x8*>(&As[r * APITCH + kh + 8]) = b1;
    }
    // --- stage B: 64 n-rows x 32 k of Wt (already bf16, contiguous) ---
    {
      const int nr = tid >> 2;            // 0..63
      const int q = (tid & 3) * 8;        // 0,8,16,24
      bf16x8 b = *reinterpret_cast<const bf16x8*>(
          Wt + (size_t)(n0 + nr) * D_FEAT + k0 + q);
      *reinterpret_cast<bf16x8*>(&Bs[nr * APITCH + q]) = b;
    }
    __syncthreads();

    bf16x8 a[2], b[4];
#pragma unroll
    for (int rg = 0; rg < 2; ++rg)
      a[rg] = *reinterpret_cast<const bf16x8*>(
          &As[(wave * 32 + rg * 16 + l15) * APITCH + kh8]);
#pragma unroll
    for (int cg = 0; cg < 4; ++cg)
      b[cg] = *reinterpret_cast<const bf16x8*>(
          &Bs[(cg * 16 + l15) * APITCH + kh8]);
#pragma unroll
    for (int rg = 0; rg < 2; ++rg)
#pragma unroll
      for (int cg = 0; cg < 4; ++cg)
        acc[rg][cg] = __builtin_amdgcn_mfma_f32_16x16x32_bf16(
            a[rg], b[cg], acc[rg][cg], 0, 0, 0);
    __syncthreads();
  }

  // epilogue: D col = l&15, row = (l>>4)*4 + r
#pragma unroll
  for (int rg = 0; rg < 2; ++rg) {
    const int rbase = m0 + wave * 32 + rg * 16 + (lane >> 4) * 4;
#pragma unroll
    for (int cg = 0; cg < 4; ++cg) {
      const int c = n0 + cg * 16 + l15;
#pragma unroll
      for (int r = 0; r < 4; ++r) {
        const int row = rbase + r;
        if (row < M) S[(size_t)row * D_FEAT + c] = (__bf16)acc[rg][cg][r];
      }
    }
  }
}

// ---------------------------------------------------------------------------
// Kernel 2: rowptr via binary search on sorted adj_row
// ---------------------------------------------------------------------------
__global__ __launch_bounds__(256) void build_rowptr(
    const int* __restrict__ rows, int E, int* __restrict__ ptr, int N) {
  const int n = blockIdx.x * blockDim.x + threadIdx.x;
  if (n > N) return;
  int lo = 0, hi = E;
  while (lo < hi) {
    const int mid = (lo + hi) >> 1;
    if (rows[mid] < n) lo = mid + 1; else hi = mid;
  }
  ptr[n] = lo;
}

// ---------------------------------------------------------------------------
// Kernel 3: out[n] = bias + sum val[e]*S_bf16[col[e]]  (wave per node,
// lane = 4 feats = 8B gather per edge, unroll-2 for ILP)
// ---------------------------------------------------------------------------
__global__ __launch_bounds__(256) void spmm_rows(
    const __bf16* __restrict__ S, const int* __restrict__ ptr,
    const int* __restrict__ col, const float* __restrict__ val,
    const float* __restrict__ bias, float* __restrict__ out, int N) {
  const int wave = threadIdx.x >> 6;
  const int lane = threadIdx.x & 63;
  const int n = blockIdx.x * 4 + wave;
  if (n >= N) return;

  const int e0 = ptr[n];
  const int e1 = ptr[n + 1];
  const int f0 = lane * 4;

  float a0 = 0.f, a1 = 0.f, a2 = 0.f, a3 = 0.f;
  int e = e0;
  for (; e + 1 < e1; e += 2) {
    const int c0 = col[e];
    const int c1 = col[e + 1];
    const float v0 = val[e];
    const float v1 = val[e + 1];
    bf16x4 s0 = *reinterpret_cast<const bf16x4*>(S + (size_t)c0 * D_FEAT + f0);
    bf16x4 s1 = *reinterpret_cast<const bf16x4*>(S + (size_t)c1 * D_FEAT + f0);
    a0 += v0 * (float)s0[0] + v1 * (float)s1[0];
    a1 += v0 * (float)s0[1] + v1 * (float)s1[1];
    a2 += v0 * (float)s0[2] + v1 * (float)s1[2];
    a3 += v0 * (float)s0[3] + v1 * (float)s1[3];
  }
  if (e < e1) {
    const int c0 = col[e];
    const float v0 = val[e];
    bf16x4 s0 = *reinterpret_cast<const bf16x4*>(S + (size_t)c0 * D_FEAT + f0);
    a0 += v0 * (float)s0[0];
    a1 += v0 * (float)s0[1];
    a2 += v0 * (float)s0[2];
    a3 += v0 * (float)s0[3];
  }
  const float4 b = *reinterpret_cast<const float4*>(bias + f0);
  float4 o = make_float4(a0 + b.x, a1 + b.y, a2 + b.z, a3 + b.w);
  *reinterpret_cast<float4*>(out + (size_t)n * D_FEAT + f0) = o;
}

// ---------------------------------------------------------------------------
extern "C" void kernel_launch(void* const* d_in, const int* in_sizes, int n_in,
                              void* d_out, int out_size, void* d_ws, size_t ws_size,
                              hipStream_t stream) {
  const float* x       = (const float*)d_in[0];
  const int*   adj_row = (const int*)d_in[1];
  const int*   adj_col = (const int*)d_in[2];
  const float* adj_val = (const float*)d_in[3];
  const float* weight  = (const float*)d_in[4];
  const float* bias    = (const float*)d_in[5];
  float*       out     = (float*)d_out;

  const int N = in_sizes[0] / D_FEAT;   // 100000
  const int E = in_sizes[1];            // 3200000

  // ws layout: Wt bf16 [256*256] | support bf16 [N*256] | rowptr int [N+1]
  __bf16* Wt      = (__bf16*)d_ws;
  __bf16* support = Wt + 256 * 256;
  int*    rowptr  = (int*)(support + (size_t)N * D_FEAT);

  cast_wt<<<256, 256, 0, stream>>>(weight, Wt);

  {
    dim3 grid((N + 127) / 128, D_FEAT / 64);
    gemm_mfma<<<grid, 256, 0, stream>>>(x, Wt, support, N);
  }
  {
    const int threads = 256;
    const int blocks = (N + 1 + threads - 1) / threads;
    build_rowptr<<<blocks, threads, 0, stream>>>(adj_row, E, rowptr, N);
  }
  {
    const int blocks = (N + 3) / 4;
    spmm_rows<<<blocks, 256, 0, stream>>>(support, rowptr, adj_col, adj_val,
                                          bias, out, N);
  }
}

// Round 3
// 305.784 us; speedup vs baseline: 2.3319x; 1.0415x over previous
//
#include <hip/hip_runtime.h>
#include <hip/hip_bf16.h>

#define D_FEAT 256

typedef __attribute__((ext_vector_type(8))) __bf16 bf16x8;
typedef __attribute__((ext_vector_type(4))) float f32x4;

// ---------------------------------------------------------------------------
// Kernel 0: Wt[n][k] = bf16(W[k][n])   (256x256, tiny)
// ---------------------------------------------------------------------------
__global__ __launch_bounds__(256) void cast_wt(
    const float* __restrict__ W, __bf16* __restrict__ Wt) {
  const int n = blockIdx.x;
  const int k = threadIdx.x;
  Wt[n * 256 + k] = (__bf16)W[k * 256 + n];
}

// ---------------------------------------------------------------------------
// Kernel 1: S = bf16( X @ W )  via mfma_f32_16x16x32_bf16
// Grid: x = n-tiles (4), y = m-tiles  -> blocks sharing an X tile are
// dispatch-adjacent (X fetched ~once from HBM, not 4x).
// Reg-prefetch of next A fp32 tile overlaps HBM latency with MFMA.
// ---------------------------------------------------------------------------
#define APITCH 40  // bf16 elems per row (pad 32->40)

__global__ __launch_bounds__(256) void gemm_mfma(
    const float* __restrict__ X, const __bf16* __restrict__ Wt,
    __bf16* __restrict__ S, int M) {
  __shared__ __bf16 As[128 * APITCH];  // 10 KiB
  __shared__ __bf16 Bs[64 * APITCH];   // 5 KiB
  const int tid = threadIdx.x;
  const int wave = tid >> 6;
  const int lane = tid & 63;
  const int m0 = blockIdx.y * 128;
  const int n0 = blockIdx.x * 64;

  f32x4 acc[2][4] = {};

  const int l15 = lane & 15;
  const int kh8 = (lane >> 4) * 8;

  // A-staging geometry: thread -> (row r, k-half kh)
  const int r = tid >> 1;            // 0..127
  const int kh = (tid & 1) * 16;     // 0 or 16
  const int gr = m0 + r;
  const bool valid = gr < M;
  const float* xsrc = X + (size_t)(valid ? gr : 0) * D_FEAT + kh;

  float4 pre[4];
#pragma unroll
  for (int q = 0; q < 4; ++q)
    pre[q] = valid ? *reinterpret_cast<const float4*>(xsrc + q * 4)
                   : make_float4(0.f, 0.f, 0.f, 0.f);

  const int nr = tid >> 2;           // B staging: 0..63
  const int q4 = (tid & 3) * 8;      // 0,8,16,24

  for (int k0 = 0; k0 < D_FEAT; k0 += 32) {
    // issue B global load early
    bf16x8 wb = *reinterpret_cast<const bf16x8*>(
        Wt + (size_t)(n0 + nr) * D_FEAT + k0 + q4);

    // convert prefetched A regs -> LDS
    bf16x8 a0, a1;
    a0[0] = (__bf16)pre[0].x; a0[1] = (__bf16)pre[0].y;
    a0[2] = (__bf16)pre[0].z; a0[3] = (__bf16)pre[0].w;
    a0[4] = (__bf16)pre[1].x; a0[5] = (__bf16)pre[1].y;
    a0[6] = (__bf16)pre[1].z; a0[7] = (__bf16)pre[1].w;
    a1[0] = (__bf16)pre[2].x; a1[1] = (__bf16)pre[2].y;
    a1[2] = (__bf16)pre[2].z; a1[3] = (__bf16)pre[2].w;
    a1[4] = (__bf16)pre[3].x; a1[5] = (__bf16)pre[3].y;
    a1[6] = (__bf16)pre[3].z; a1[7] = (__bf16)pre[3].w;
    *reinterpret_cast<bf16x8*>(&As[r * APITCH + kh]) = a0;
    *reinterpret_cast<bf16x8*>(&As[r * APITCH + kh + 8]) = a1;
    *reinterpret_cast<bf16x8*>(&Bs[nr * APITCH + q4]) = wb;

    // prefetch next A fp32 tile into regs (overlaps with MFMA below)
    const bool have = (k0 + 32) < D_FEAT;
    float4 nxt[4];
    if (have && valid) {
#pragma unroll
      for (int q = 0; q < 4; ++q)
        nxt[q] = *reinterpret_cast<const float4*>(xsrc + k0 + 32 + q * 4);
    }
    __syncthreads();

    bf16x8 a[2], b[4];
#pragma unroll
    for (int rg = 0; rg < 2; ++rg)
      a[rg] = *reinterpret_cast<const bf16x8*>(
          &As[(wave * 32 + rg * 16 + l15) * APITCH + kh8]);
#pragma unroll
    for (int cg = 0; cg < 4; ++cg)
      b[cg] = *reinterpret_cast<const bf16x8*>(
          &Bs[(cg * 16 + l15) * APITCH + kh8]);
#pragma unroll
    for (int rg = 0; rg < 2; ++rg)
#pragma unroll
      for (int cg = 0; cg < 4; ++cg)
        acc[rg][cg] = __builtin_amdgcn_mfma_f32_16x16x32_bf16(
            a[rg], b[cg], acc[rg][cg], 0, 0, 0);
    __syncthreads();

    if (have && valid) {
#pragma unroll
      for (int q = 0; q < 4; ++q) pre[q] = nxt[q];
    }
  }

  // epilogue: D col = l&15, row = (l>>4)*4 + r
#pragma unroll
  for (int rg = 0; rg < 2; ++rg) {
    const int rbase = m0 + wave * 32 + rg * 16 + (lane >> 4) * 4;
#pragma unroll
    for (int cg = 0; cg < 4; ++cg) {
      const int c = n0 + cg * 16 + l15;
#pragma unroll
      for (int rr = 0; rr < 4; ++rr) {
        const int row = rbase + rr;
        if (row < M) S[(size_t)row * D_FEAT + c] = (__bf16)acc[rg][cg][rr];
      }
    }
  }
}

// ---------------------------------------------------------------------------
// Kernel 2: rowptr via binary search on sorted adj_row
// ---------------------------------------------------------------------------
__global__ __launch_bounds__(256) void build_rowptr(
    const int* __restrict__ rows, int E, int* __restrict__ ptr, int N) {
  const int n = blockIdx.x * blockDim.x + threadIdx.x;
  if (n > N) return;
  int lo = 0, hi = E;
  while (lo < hi) {
    const int mid = (lo + hi) >> 1;
    if (rows[mid] < n) lo = mid + 1; else hi = mid;
  }
  ptr[n] = lo;
}

// ---------------------------------------------------------------------------
// Kernel 3: out[n] = bias + sum val[e]*S[col[e]]
// Wave per node. Half-wave 0 gathers even edges, half-wave 1 odd edges;
// lane covers 8 features (16B bf16x8) -> one 1KB wave-gather per 2 edges.
// unroll 4 -> 4KB outstanding gather bytes per wave. NT stores for out.
// ---------------------------------------------------------------------------
__global__ __launch_bounds__(256) void spmm_rows(
    const __bf16* __restrict__ S, const int* __restrict__ ptr,
    const int* __restrict__ col, const float* __restrict__ val,
    const float* __restrict__ bias, float* __restrict__ out, int N) {
  const int wave = threadIdx.x >> 6;
  const int lane = threadIdx.x & 63;
  const int n = blockIdx.x * 4 + wave;
  if (n >= N) return;

  const int e0 = ptr[n];
  const int e1 = ptr[n + 1];
  const int hw = lane >> 5;        // 0: even edges, 1: odd edges
  const int l5 = lane & 31;        // feature group
  const int f0 = l5 * 8;

  float acc[8] = {};
  const int deg = e1 - e0;
  const int nit = (deg + 1) >> 1;

#pragma unroll 4
  for (int it = 0; it < nit; ++it) {
    const int e = e0 + 2 * it + hw;
    int c = 0;
    float v = 0.f;
    if (e < e1) { c = col[e]; v = val[e]; }
    bf16x8 s = *reinterpret_cast<const bf16x8*>(S + (size_t)c * D_FEAT + f0);
#pragma unroll
    for (int j = 0; j < 8; ++j) acc[j] += v * (float)s[j];
  }

  // combine half-waves: partner lane is lane ^ 32
#pragma unroll
  for (int j = 0; j < 8; ++j) acc[j] += __shfl(acc[j], lane ^ 32, 64);

  // lane (hw,l5) writes float4 at feature f0 + hw*4  (static acc indexing)
  const int fw = f0 + hw * 4;
  const float4 b = *reinterpret_cast<const float4*>(bias + fw);
  const float r0 = hw ? acc[4] : acc[0];
  const float r1 = hw ? acc[5] : acc[1];
  const float r2 = hw ? acc[6] : acc[2];
  const float r3 = hw ? acc[7] : acc[3];
  f32x4 o;
  o[0] = r0 + b.x; o[1] = r1 + b.y; o[2] = r2 + b.z; o[3] = r3 + b.w;
  __builtin_nontemporal_store(
      o, reinterpret_cast<f32x4*>(out + (size_t)n * D_FEAT + fw));
}

// ---------------------------------------------------------------------------
extern "C" void kernel_launch(void* const* d_in, const int* in_sizes, int n_in,
                              void* d_out, int out_size, void* d_ws, size_t ws_size,
                              hipStream_t stream) {
  const float* x       = (const float*)d_in[0];
  const int*   adj_row = (const int*)d_in[1];
  const int*   adj_col = (const int*)d_in[2];
  const float* adj_val = (const float*)d_in[3];
  const float* weight  = (const float*)d_in[4];
  const float* bias    = (const float*)d_in[5];
  float*       out     = (float*)d_out;

  const int N = in_sizes[0] / D_FEAT;   // 100000
  const int E = in_sizes[1];            // 3200000

  // ws layout: Wt bf16 [256*256] | support bf16 [N*256] | rowptr int [N+1]
  __bf16* Wt      = (__bf16*)d_ws;
  __bf16* support = Wt + 256 * 256;
  int*    rowptr  = (int*)(support + (size_t)N * D_FEAT);

  cast_wt<<<256, 256, 0, stream>>>(weight, Wt);

  {
    dim3 grid(D_FEAT / 64, (N + 127) / 128);
    gemm_mfma<<<grid, 256, 0, stream>>>(x, Wt, support, N);
  }
  {
    const int threads = 256;
    const int blocks = (N + 1 + threads - 1) / threads;
    build_rowptr<<<blocks, threads, 0, stream>>>(adj_row, E, rowptr, N);
  }
  {
    const int blocks = (N + 3) / 4;
    spmm_rows<<<blocks, 256, 0, stream>>>(support, rowptr, adj_col, adj_val,
                                          bias, out, N);
  }
}

// Round 4
// 294.743 us; speedup vs baseline: 2.4192x; 1.0375x over previous
//
#include <hip/hip_runtime.h>
#include <hip/hip_bf16.h>

#define D_FEAT 256

typedef __attribute__((ext_vector_type(8))) __bf16 bf16x8;
typedef __attribute__((ext_vector_type(4))) float f32x4;

// ---------------------------------------------------------------------------
// Kernel 0: Wt[n][k] = bf16(W[k][n])   (256x256, tiny)
// ---------------------------------------------------------------------------
__global__ __launch_bounds__(256) void cast_wt(
    const float* __restrict__ W, __bf16* __restrict__ Wt) {
  const int n = blockIdx.x;
  const int k = threadIdx.x;
  Wt[n * 256 + k] = (__bf16)W[k * 256 + n];
}

// ---------------------------------------------------------------------------
// Kernel 1: S = bf16( X @ W )  via mfma_f32_16x16x32_bf16
// Tile BM=128, BN=128, BK=32; 4 waves, wave = 32 rows x 128 cols
// (2x8 fragments, 16 MFMA per K-step vs 10 ds_read_b128).
// A fp32->bf16 convert fused in staging, reg-prefetched across the barrier.
// ---------------------------------------------------------------------------
#define APITCH 40  // bf16 elems per row (pad 32->40; 2-way LDS alias = free)

__global__ __launch_bounds__(256) void gemm_mfma(
    const float* __restrict__ X, const __bf16* __restrict__ Wt,
    __bf16* __restrict__ S, int M) {
  __shared__ __bf16 As[128 * APITCH];  // 10 KiB
  __shared__ __bf16 Bs[128 * APITCH];  // 10 KiB
  const int tid = threadIdx.x;
  const int wave = tid >> 6;
  const int lane = tid & 63;
  const int m0 = blockIdx.y * 128;
  const int n0 = blockIdx.x * 128;

  f32x4 acc[2][8] = {};

  const int l15 = lane & 15;
  const int kh8 = (lane >> 4) * 8;

  // A-staging geometry: thread -> (row r, k-half kh)
  const int r = tid >> 1;            // 0..127
  const int kh = (tid & 1) * 16;     // 0 or 16
  const int gr = m0 + r;
  const bool valid = gr < M;
  const float* xsrc = X + (size_t)(valid ? gr : 0) * D_FEAT + kh;

  float4 pre[4];
#pragma unroll
  for (int q = 0; q < 4; ++q)
    pre[q] = valid ? *reinterpret_cast<const float4*>(xsrc + q * 4)
                   : make_float4(0.f, 0.f, 0.f, 0.f);

  // B-staging geometry: thread -> (n-row nr, 16-k half qb)
  const int nr = tid >> 1;           // 0..127
  const int qb = (tid & 1) * 16;     // 0 or 16

  for (int k0 = 0; k0 < D_FEAT; k0 += 32) {
    // issue B global loads early (Wt already bf16, rows contiguous)
    const __bf16* wsrc = Wt + (size_t)(n0 + nr) * D_FEAT + k0 + qb;
    bf16x8 wb0 = *reinterpret_cast<const bf16x8*>(wsrc);
    bf16x8 wb1 = *reinterpret_cast<const bf16x8*>(wsrc + 8);

    // convert prefetched A regs -> LDS
    bf16x8 a0, a1;
    a0[0] = (__bf16)pre[0].x; a0[1] = (__bf16)pre[0].y;
    a0[2] = (__bf16)pre[0].z; a0[3] = (__bf16)pre[0].w;
    a0[4] = (__bf16)pre[1].x; a0[5] = (__bf16)pre[1].y;
    a0[6] = (__bf16)pre[1].z; a0[7] = (__bf16)pre[1].w;
    a1[0] = (__bf16)pre[2].x; a1[1] = (__bf16)pre[2].y;
    a1[2] = (__bf16)pre[2].z; a1[3] = (__bf16)pre[2].w;
    a1[4] = (__bf16)pre[3].x; a1[5] = (__bf16)pre[3].y;
    a1[6] = (__bf16)pre[3].z; a1[7] = (__bf16)pre[3].w;
    *reinterpret_cast<bf16x8*>(&As[r * APITCH + kh]) = a0;
    *reinterpret_cast<bf16x8*>(&As[r * APITCH + kh + 8]) = a1;
    *reinterpret_cast<bf16x8*>(&Bs[nr * APITCH + qb]) = wb0;
    *reinterpret_cast<bf16x8*>(&Bs[nr * APITCH + qb + 8]) = wb1;

    // prefetch next A fp32 tile into regs (overlaps with MFMA below)
    const bool have = (k0 + 32) < D_FEAT;
    float4 nxt[4];
    if (have && valid) {
#pragma unroll
      for (int q = 0; q < 4; ++q)
        nxt[q] = *reinterpret_cast<const float4*>(xsrc + k0 + 32 + q * 4);
    }
    __syncthreads();

    bf16x8 a[2], b[8];
#pragma unroll
    for (int rg = 0; rg < 2; ++rg)
      a[rg] = *reinterpret_cast<const bf16x8*>(
          &As[(wave * 32 + rg * 16 + l15) * APITCH + kh8]);
#pragma unroll
    for (int cg = 0; cg < 8; ++cg)
      b[cg] = *reinterpret_cast<const bf16x8*>(
          &Bs[(cg * 16 + l15) * APITCH + kh8]);
#pragma unroll
    for (int rg = 0; rg < 2; ++rg)
#pragma unroll
      for (int cg = 0; cg < 8; ++cg)
        acc[rg][cg] = __builtin_amdgcn_mfma_f32_16x16x32_bf16(
            a[rg], b[cg], acc[rg][cg], 0, 0, 0);
    __syncthreads();

    if (have && valid) {
#pragma unroll
      for (int q = 0; q < 4; ++q) pre[q] = nxt[q];
    }
  }

  // epilogue: D col = l&15, row = (l>>4)*4 + r
#pragma unroll
  for (int rg = 0; rg < 2; ++rg) {
    const int rbase = m0 + wave * 32 + rg * 16 + (lane >> 4) * 4;
#pragma unroll
    for (int cg = 0; cg < 8; ++cg) {
      const int c = n0 + cg * 16 + l15;
#pragma unroll
      for (int rr = 0; rr < 4; ++rr) {
        const int row = rbase + rr;
        if (row < M) S[(size_t)row * D_FEAT + c] = (__bf16)acc[rg][cg][rr];
      }
    }
  }
}

// ---------------------------------------------------------------------------
// Kernel 2: rowptr via binary search on sorted adj_row
// ---------------------------------------------------------------------------
__global__ __launch_bounds__(256) void build_rowptr(
    const int* __restrict__ rows, int E, int* __restrict__ ptr, int N) {
  const int n = blockIdx.x * blockDim.x + threadIdx.x;
  if (n > N) return;
  int lo = 0, hi = E;
  while (lo < hi) {
    const int mid = (lo + hi) >> 1;
    if (rows[mid] < n) lo = mid + 1; else hi = mid;
  }
  ptr[n] = lo;
}

// ---------------------------------------------------------------------------
// Kernel 3: out[n] = bias + sum val[e]*S[col[e]]
// Wave per node; half-wave h handles edges of parity h; lane covers 8 feats
// (16B). Inner loop: batches of 16 edges -> 8 hoisted col/val loads + 8
// independent 1KB wave-gathers in flight. col/val read nontemporal (streamed
// once; keep them out of L2 so S rows stay resident).
// ---------------------------------------------------------------------------
__global__ __launch_bounds__(256) void spmm_rows(
    const __bf16* __restrict__ S, const int* __restrict__ ptr,
    const int* __restrict__ col, const float* __restrict__ val,
    const float* __restrict__ bias, float* __restrict__ out, int N) {
  const int wave = threadIdx.x >> 6;
  const int lane = threadIdx.x & 63;
  const int n = blockIdx.x * 4 + wave;
  if (n >= N) return;

  const int e0 = ptr[n];
  const int e1 = ptr[n + 1];
  const int hw = lane >> 5;        // 0: even edges, 1: odd edges
  const int f0 = (lane & 31) * 8;  // feature group (8 bf16 = 16B)

  float acc[8] = {};
  const int deg = e1 - e0;
  const int nb = deg >> 4;         // full batches of 16 edges

  int e = e0;
  for (int b = 0; b < nb; ++b) {
    int cc[8];
    float vv[8];
#pragma unroll
    for (int i = 0; i < 8; ++i) {
      cc[i] = __builtin_nontemporal_load(col + e + 2 * i + hw);
      vv[i] = __builtin_nontemporal_load(val + e + 2 * i + hw);
    }
#pragma unroll
    for (int i = 0; i < 8; ++i) {
      bf16x8 s = *reinterpret_cast<const bf16x8*>(S + (size_t)cc[i] * D_FEAT + f0);
#pragma unroll
      for (int j = 0; j < 8; ++j) acc[j] += vv[i] * (float)s[j];
    }
    e += 16;
  }
  // tail (mixed-parity guarded)
  for (; e < e1; e += 2) {
    const int ee = e + hw;
    int c = 0;
    float v = 0.f;
    if (ee < e1) { c = col[ee]; v = val[ee]; }
    bf16x8 s = *reinterpret_cast<const bf16x8*>(S + (size_t)c * D_FEAT + f0);
#pragma unroll
    for (int j = 0; j < 8; ++j) acc[j] += v * (float)s[j];
  }

  // combine half-waves: partner lane is lane ^ 32
#pragma unroll
  for (int j = 0; j < 8; ++j) acc[j] += __shfl(acc[j], lane ^ 32, 64);

  // lane (hw, l5) writes float4 at feature f0 + hw*4 (static acc indexing)
  const int fw = f0 + hw * 4;
  const float4 b = *reinterpret_cast<const float4*>(bias + fw);
  const float r0 = hw ? acc[4] : acc[0];
  const float r1 = hw ? acc[5] : acc[1];
  const float r2 = hw ? acc[6] : acc[2];
  const float r3 = hw ? acc[7] : acc[3];
  f32x4 o;
  o[0] = r0 + b.x; o[1] = r1 + b.y; o[2] = r2 + b.z; o[3] = r3 + b.w;
  __builtin_nontemporal_store(
      o, reinterpret_cast<f32x4*>(out + (size_t)n * D_FEAT + fw));
}

// ---------------------------------------------------------------------------
extern "C" void kernel_launch(void* const* d_in, const int* in_sizes, int n_in,
                              void* d_out, int out_size, void* d_ws, size_t ws_size,
                              hipStream_t stream) {
  const float* x       = (const float*)d_in[0];
  const int*   adj_row = (const int*)d_in[1];
  const int*   adj_col = (const int*)d_in[2];
  const float* adj_val = (const float*)d_in[3];
  const float* weight  = (const float*)d_in[4];
  const float* bias    = (const float*)d_in[5];
  float*       out     = (float*)d_out;

  const int N = in_sizes[0] / D_FEAT;   // 100000
  const int E = in_sizes[1];            // 3200000

  // ws layout: Wt bf16 [256*256] | support bf16 [N*256] | rowptr int [N+1]
  __bf16* Wt      = (__bf16*)d_ws;
  __bf16* support = Wt + 256 * 256;
  int*    rowptr  = (int*)(support + (size_t)N * D_FEAT);

  cast_wt<<<256, 256, 0, stream>>>(weight, Wt);

  {
    dim3 grid(D_FEAT / 128, (N + 127) / 128);
    gemm_mfma<<<grid, 256, 0, stream>>>(x, Wt, support, N);
  }
  {
    const int threads = 256;
    const int blocks = (N + 1 + threads - 1) / threads;
    build_rowptr<<<blocks, threads, 0, stream>>>(adj_row, E, rowptr, N);
  }
  {
    const int blocks = (N + 3) / 4;
    spmm_rows<<<blocks, 256, 0, stream>>>(support, rowptr, adj_col, adj_val,
                                          bias, out, N);
  }
}

// Round 5
// 284.229 us; speedup vs baseline: 2.5087x; 1.0370x over previous
//
#include <hip/hip_runtime.h>
#include <hip/hip_bf16.h>

#define D_FEAT 256

typedef __attribute__((ext_vector_type(8))) __bf16 bf16x8;
typedef __attribute__((ext_vector_type(4))) float f32x4;

// ---------------------------------------------------------------------------
// Kernel 0: Wt[n][k] = bf16(W[k][n])   (256x256, tiny)
// ---------------------------------------------------------------------------
__global__ __launch_bounds__(256) void cast_wt(
    const float* __restrict__ W, __bf16* __restrict__ Wt) {
  const int n = blockIdx.x;
  const int k = threadIdx.x;
  Wt[n * 256 + k] = (__bf16)W[k * 256 + n];
}

// ---------------------------------------------------------------------------
// Kernel 1: S = bf16( X @ W )  via mfma_f32_16x16x32_bf16
// Tile BM=128, BN=128, BK=32; 4 waves, wave = 32 rows x 128 cols
// (16 MFMA per K-step vs 10 ds_read_b128). A fp32->bf16 convert fused in
// staging, reg-prefetched across the barrier.
// ---------------------------------------------------------------------------
#define APITCH 40  // bf16 elems per row (pad 32->40; 2-way LDS alias = free)

__global__ __launch_bounds__(256) void gemm_mfma(
    const float* __restrict__ X, const __bf16* __restrict__ Wt,
    __bf16* __restrict__ S, int M) {
  __shared__ __bf16 As[128 * APITCH];  // 10 KiB
  __shared__ __bf16 Bs[128 * APITCH];  // 10 KiB
  const int tid = threadIdx.x;
  const int wave = tid >> 6;
  const int lane = tid & 63;
  const int m0 = blockIdx.y * 128;
  const int n0 = blockIdx.x * 128;

  f32x4 acc[2][8] = {};

  const int l15 = lane & 15;
  const int kh8 = (lane >> 4) * 8;

  const int r = tid >> 1;            // 0..127
  const int kh = (tid & 1) * 16;     // 0 or 16
  const int gr = m0 + r;
  const bool valid = gr < M;
  const float* xsrc = X + (size_t)(valid ? gr : 0) * D_FEAT + kh;

  float4 pre[4];
#pragma unroll
  for (int q = 0; q < 4; ++q)
    pre[q] = valid ? *reinterpret_cast<const float4*>(xsrc + q * 4)
                   : make_float4(0.f, 0.f, 0.f, 0.f);

  const int nr = tid >> 1;           // B staging: 0..127
  const int qb = (tid & 1) * 16;     // 0 or 16

  for (int k0 = 0; k0 < D_FEAT; k0 += 32) {
    const __bf16* wsrc = Wt + (size_t)(n0 + nr) * D_FEAT + k0 + qb;
    bf16x8 wb0 = *reinterpret_cast<const bf16x8*>(wsrc);
    bf16x8 wb1 = *reinterpret_cast<const bf16x8*>(wsrc + 8);

    bf16x8 a0, a1;
    a0[0] = (__bf16)pre[0].x; a0[1] = (__bf16)pre[0].y;
    a0[2] = (__bf16)pre[0].z; a0[3] = (__bf16)pre[0].w;
    a0[4] = (__bf16)pre[1].x; a0[5] = (__bf16)pre[1].y;
    a0[6] = (__bf16)pre[1].z; a0[7] = (__bf16)pre[1].w;
    a1[0] = (__bf16)pre[2].x; a1[1] = (__bf16)pre[2].y;
    a1[2] = (__bf16)pre[2].z; a1[3] = (__bf16)pre[2].w;
    a1[4] = (__bf16)pre[3].x; a1[5] = (__bf16)pre[3].y;
    a1[6] = (__bf16)pre[3].z; a1[7] = (__bf16)pre[3].w;
    *reinterpret_cast<bf16x8*>(&As[r * APITCH + kh]) = a0;
    *reinterpret_cast<bf16x8*>(&As[r * APITCH + kh + 8]) = a1;
    *reinterpret_cast<bf16x8*>(&Bs[nr * APITCH + qb]) = wb0;
    *reinterpret_cast<bf16x8*>(&Bs[nr * APITCH + qb + 8]) = wb1;

    const bool have = (k0 + 32) < D_FEAT;
    float4 nxt[4];
    if (have && valid) {
#pragma unroll
      for (int q = 0; q < 4; ++q)
        nxt[q] = *reinterpret_cast<const float4*>(xsrc + k0 + 32 + q * 4);
    }
    __syncthreads();

    bf16x8 a[2], b[8];
#pragma unroll
    for (int rg = 0; rg < 2; ++rg)
      a[rg] = *reinterpret_cast<const bf16x8*>(
          &As[(wave * 32 + rg * 16 + l15) * APITCH + kh8]);
#pragma unroll
    for (int cg = 0; cg < 8; ++cg)
      b[cg] = *reinterpret_cast<const bf16x8*>(
          &Bs[(cg * 16 + l15) * APITCH + kh8]);
#pragma unroll
    for (int rg = 0; rg < 2; ++rg)
#pragma unroll
      for (int cg = 0; cg < 8; ++cg)
        acc[rg][cg] = __builtin_amdgcn_mfma_f32_16x16x32_bf16(
            a[rg], b[cg], acc[rg][cg], 0, 0, 0);
    __syncthreads();

    if (have && valid) {
#pragma unroll
      for (int q = 0; q < 4; ++q) pre[q] = nxt[q];
    }
  }

  // epilogue: D col = l&15, row = (l>>4)*4 + r
#pragma unroll
  for (int rg = 0; rg < 2; ++rg) {
    const int rbase = m0 + wave * 32 + rg * 16 + (lane >> 4) * 4;
#pragma unroll
    for (int cg = 0; cg < 8; ++cg) {
      const int c = n0 + cg * 16 + l15;
#pragma unroll
      for (int rr = 0; rr < 4; ++rr) {
        const int row = rbase + rr;
        if (row < M) S[(size_t)row * D_FEAT + c] = (__bf16)acc[rg][cg][rr];
      }
    }
  }
}

// ---------------------------------------------------------------------------
// Kernel 2: rowptr via binary search on sorted adj_row
// ---------------------------------------------------------------------------
__global__ __launch_bounds__(256) void build_rowptr(
    const int* __restrict__ rows, int E, int* __restrict__ ptr, int N) {
  const int n = blockIdx.x * blockDim.x + threadIdx.x;
  if (n > N) return;
  int lo = 0, hi = E;
  while (lo < hi) {
    const int mid = (lo + hi) >> 1;
    if (rows[mid] < n) lo = mid + 1; else hi = mid;
  }
  ptr[n] = lo;
}

// ---------------------------------------------------------------------------
// Kernel 3: out[n] = bias + sum val[e]*S[col[e]]
// Wave per node; half-wave h = edges of parity h; lane = 8 feats (16B).
// ALL batches are full 8-gather batches: index-clamped loads, masked val.
// No serial tail, no NT on col/val (they're L2-shared across the block).
// ---------------------------------------------------------------------------
__global__ __launch_bounds__(256) void spmm_rows(
    const __bf16* __restrict__ S, const int* __restrict__ ptr,
    const int* __restrict__ col, const float* __restrict__ val,
    const float* __restrict__ bias, float* __restrict__ out, int N) {
  const int wave = threadIdx.x >> 6;
  const int lane = threadIdx.x & 63;
  const int n = blockIdx.x * 4 + wave;
  if (n >= N) return;

  const int e0 = ptr[n];
  const int e1 = ptr[n + 1];
  const int hw = lane >> 5;        // 0: even edges, 1: odd edges
  const int f0 = (lane & 31) * 8;  // feature group (8 bf16 = 16B)

  float acc[8] = {};
  const int deg = e1 - e0;
  const int elast = e1 - 1;
  const int nit = (deg + 15) >> 4; // batches of 16 edges (8 per half-wave)

  int e = e0;
  for (int b = 0; b < nit; ++b, e += 16) {
    int cc[8];
    float vv[8];
#pragma unroll
    for (int i = 0; i < 8; ++i) {
      int ee = e + 2 * i + hw;
      const bool ok = ee <= elast;
      ee = ok ? ee : elast;
      cc[i] = col[ee];
      vv[i] = ok ? val[ee] : 0.f;
    }
#pragma unroll
    for (int i = 0; i < 8; ++i) {
      bf16x8 s = *reinterpret_cast<const bf16x8*>(S + (size_t)cc[i] * D_FEAT + f0);
#pragma unroll
      for (int j = 0; j < 8; ++j) acc[j] += vv[i] * (float)s[j];
    }
  }

  // combine half-waves: partner lane is lane ^ 32
#pragma unroll
  for (int j = 0; j < 8; ++j) acc[j] += __shfl(acc[j], lane ^ 32, 64);

  // lane (hw, l5) writes float4 at feature f0 + hw*4 (static acc indexing)
  const int fw = f0 + hw * 4;
  const float4 b = *reinterpret_cast<const float4*>(bias + fw);
  const float r0 = hw ? acc[4] : acc[0];
  const float r1 = hw ? acc[5] : acc[1];
  const float r2 = hw ? acc[6] : acc[2];
  const float r3 = hw ? acc[7] : acc[3];
  f32x4 o;
  o[0] = r0 + b.x; o[1] = r1 + b.y; o[2] = r2 + b.z; o[3] = r3 + b.w;
  __builtin_nontemporal_store(
      o, reinterpret_cast<f32x4*>(out + (size_t)n * D_FEAT + fw));
}

// ---------------------------------------------------------------------------
extern "C" void kernel_launch(void* const* d_in, const int* in_sizes, int n_in,
                              void* d_out, int out_size, void* d_ws, size_t ws_size,
                              hipStream_t stream) {
  const float* x       = (const float*)d_in[0];
  const int*   adj_row = (const int*)d_in[1];
  const int*   adj_col = (const int*)d_in[2];
  const float* adj_val = (const float*)d_in[3];
  const float* weight  = (const float*)d_in[4];
  const float* bias    = (const float*)d_in[5];
  float*       out     = (float*)d_out;

  const int N = in_sizes[0] / D_FEAT;   // 100000
  const int E = in_sizes[1];            // 3200000

  // ws layout: Wt bf16 [256*256] | support bf16 [N*256] | rowptr int [N+1]
  __bf16* Wt      = (__bf16*)d_ws;
  __bf16* support = Wt + 256 * 256;
  int*    rowptr  = (int*)(support + (size_t)N * D_FEAT);

  cast_wt<<<256, 256, 0, stream>>>(weight, Wt);

  {
    dim3 grid(D_FEAT / 128, (N + 127) / 128);
    gemm_mfma<<<grid, 256, 0, stream>>>(x, Wt, support, N);
  }
  {
    const int threads = 256;
    const int blocks = (N + 1 + threads - 1) / threads;
    build_rowptr<<<blocks, threads, 0, stream>>>(adj_row, E, rowptr, N);
  }
  {
    const int blocks = (N + 3) / 4;
    spmm_rows<<<blocks, 256, 0, stream>>>(support, rowptr, adj_col, adj_val,
                                          bias, out, N);
  }
}